// Round 1
// baseline (260.541 us; speedup 1.0000x reference)
//
#include <hip/hip_runtime.h>
#include <hip/hip_bf16.h>
#include <cstdint>
#include <cstddef>

#define NN 1024
#define FF 256

typedef __attribute__((ext_vector_type(8))) short bf16x8;
typedef __attribute__((ext_vector_type(4))) float f32x4;

__device__ __forceinline__ short f2bf(float x) {
  unsigned int u = __float_as_uint(x);
  u = (u + 0x7fffu + ((u >> 16) & 1u)) >> 16;   // RNE
  return (short)u;
}

// ---------------- d = (rowsum(adj)+1)^-1/2, one wave per row ----------------
__global__ __launch_bounds__(256)
void compute_dinv(const float* __restrict__ adj, float* __restrict__ dinv) {
  int wid = threadIdx.x >> 6, lane = threadIdx.x & 63;
  int row = (blockIdx.x << 2) + wid;           // 0..32767
  const float4* r = (const float4*)(adj + (size_t)row * NN);
  float s = 0.f;
  #pragma unroll
  for (int i = 0; i < 4; i++) {
    float4 v = r[lane + (i << 6)];
    s += (v.x + v.y) + (v.z + v.w);
  }
  #pragma unroll
  for (int off = 32; off > 0; off >>= 1) s += __shfl_down(s, off, 64);
  if (lane == 0) dinv[row] = rsqrtf(s + 1.0f);
}

// ---------------- X [bw][n][256] fp32 -> XT [bw][256][1024] bf16 ------------
__global__ __launch_bounds__(256)
void transpose_x(const float* __restrict__ X, short* __restrict__ XT) {
  __shared__ short T[64][72];                  // 64n x 64f tile, padded
  int bwo = blockIdx.z;
  int n0 = blockIdx.x << 6, f0 = blockIdx.y << 6;
  int t = threadIdx.x;
  {
    int n = t >> 2, fc = (t & 3) << 4;
    const float* src = X + (((size_t)bwo * NN + n0 + n) * FF) + f0 + fc;
    #pragma unroll
    for (int i = 0; i < 4; i++) {
      float4 v = ((const float4*)src)[i];
      ushort4 p;
      p.x = (unsigned short)f2bf(v.x); p.y = (unsigned short)f2bf(v.y);
      p.z = (unsigned short)f2bf(v.z); p.w = (unsigned short)f2bf(v.w);
      *(ushort4*)&T[n][fc + (i << 2)] = p;
    }
  }
  __syncthreads();
  {
    int f = t >> 2, nc = (t & 3) << 4;
    short* dst = XT + (((size_t)bwo * FF + f0 + f) * NN) + n0 + nc;
    short tmp[16];
    #pragma unroll
    for (int i = 0; i < 16; i++) tmp[i] = T[nc + i][f];
    *(int4*)dst = *(int4*)&tmp[0];
    *(int4*)(dst + 8) = *(int4*)&tmp[8];
  }
}

// ---------------- W [256][FO] fp32 -> WT [FO][256] bf16 ---------------------
__global__ __launch_bounds__(256)
void transpose_w(const float* __restrict__ W, short* __restrict__ WT, int FO) {
  int idx = blockIdx.x * 256 + threadIdx.x;    // over FO*256
  if (idx >= FO * 256) return;
  int fo = idx >> 8, fi = idx & 255;
  WT[idx] = f2bf(W[fi * FO + fo]);
}

// ---------------- fused layer: HTout = relu((Anorm @ HTin^T) @ W + b)^T -----
// HTin: [32][256][1024] bf16 (features-major).  256 blocks x 512 threads.
// Each wave: 32 rows x 128 agg-cols (stage 1), then 32 rows x F_OUT/2 (stage 2).
template<int F_OUT, bool FINAL>
__global__ __launch_bounds__(512, 2)
void gcn_layer(const float* __restrict__ adj,
               const float* __restrict__ dinv,
               const short* __restrict__ HTin,
               const short* __restrict__ WT,      // [F_OUT][256] bf16
               const float* __restrict__ bias,    // [F_OUT] fp32
               short* __restrict__ HTout,         // [32][F_OUT][1024] bf16
               float* __restrict__ Out) {         // [32][1024][F_OUT] fp32
  static_assert(F_OUT == 128 || F_OUT == 256, "");
  __shared__ short Hs[256][40];                // H tiles (stage1) / WT tiles (stage2)
  __shared__ short aggL[8][32][136];           // per-wave agg (stride 272B: bank-clean)

  // XCD-aware decode: blocks b%8 -> same XCD get bws {4j..4j+3}
  int b = blockIdx.x;
  int bw = ((b & 7) << 2) + ((b >> 3) & 3);
  int rb = b >> 5;                             // 0..7
  int r0 = rb << 7;                            // 128 rows / block

  int tid = threadIdx.x;
  int wid = tid >> 6, lane = tid & 63;
  int l15 = lane & 15, l4 = lane >> 4;
  int wm = wid >> 1, wn = wid & 1;

  const float* adjB = adj + (size_t)bw * NN * NN;
  const float* dvB  = dinv + bw * NN;
  const short* HTb  = HTin + (size_t)bw * FF * NN;

  int rowbase = r0 + (wm << 5);
  int row0 = rowbase + l15;
  int row1 = rowbase + 16 + l15;
  float dr0 = dvB[row0], dr1 = dvB[row1];

  f32x4 acc[2][8];
  #pragma unroll
  for (int am = 0; am < 2; am++)
    #pragma unroll
    for (int nf = 0; nf < 8; nf++) acc[am][nf] = f32x4{0.f, 0.f, 0.f, 0.f};

  // ---------- stage 1: agg = Anorm @ H (K = 1024) ----------
  for (int k0 = 0; k0 < NN; k0 += 32) {
    __syncthreads();                           // protect Hs reuse
    {
      int f = tid >> 1, half = tid & 1;        // stage Hs[f][0..31] = HT[f][k0..+31]
      const int4* src = (const int4*)(HTb + (size_t)f * NN + k0 + (half << 4));
      int4 v0 = src[0], v1 = src[1];
      *(int4*)&Hs[f][half << 4] = v0;
      *(int4*)&Hs[f][(half << 4) + 8] = v1;
    }
    int kb = k0 + (l4 << 3);
    float dk[8];
    {
      float4 d0 = *(const float4*)(dvB + kb);
      float4 d1 = *(const float4*)(dvB + kb + 4);
      dk[0]=d0.x; dk[1]=d0.y; dk[2]=d0.z; dk[3]=d0.w;
      dk[4]=d1.x; dk[5]=d1.y; dk[6]=d1.z; dk[7]=d1.w;
    }
    union { short s[8]; bf16x8 v; } af0, af1;
    {
      const float* ap = adjB + (size_t)row0 * NN + kb;
      float4 a0 = *(const float4*)ap, a1 = *(const float4*)(ap + 4);
      float av[8] = {a0.x,a0.y,a0.z,a0.w,a1.x,a1.y,a1.z,a1.w};
      #pragma unroll
      for (int j = 0; j < 8; j++) {
        float v = av[j] + ((row0 == kb + j) ? 1.f : 0.f);
        af0.s[j] = f2bf(v * dr0 * dk[j]);
      }
    }
    {
      const float* ap = adjB + (size_t)row1 * NN + kb;
      float4 a0 = *(const float4*)ap, a1 = *(const float4*)(ap + 4);
      float av[8] = {a0.x,a0.y,a0.z,a0.w,a1.x,a1.y,a1.z,a1.w};
      #pragma unroll
      for (int j = 0; j < 8; j++) {
        float v = av[j] + ((row1 == kb + j) ? 1.f : 0.f);
        af1.s[j] = f2bf(v * dr1 * dk[j]);
      }
    }
    __syncthreads();                           // Hs ready
    #pragma unroll
    for (int nf = 0; nf < 8; nf++) {
      bf16x8 bv = *(const bf16x8*)&Hs[(wn << 7) + (nf << 4) + l15][l4 << 3];
      acc[0][nf] = __builtin_amdgcn_mfma_f32_16x16x32_bf16(af0.v, bv, acc[0][nf], 0, 0, 0);
      acc[1][nf] = __builtin_amdgcn_mfma_f32_16x16x32_bf16(af1.v, bv, acc[1][nf], 0, 0, 0);
    }
  }

  // spill agg (bf16) to per-wave LDS region: aggL[wid][local row 0..31][col 0..127]
  #pragma unroll
  for (int am = 0; am < 2; am++)
    #pragma unroll
    for (int nf = 0; nf < 8; nf++)
      #pragma unroll
      for (int j = 0; j < 4; j++)
        aggL[wid][(am << 4) + (l4 << 2) + j][(nf << 4) + l15] = f2bf(acc[am][nf][j]);

  // ---------- stage 2: out = relu(agg @ W + b) (K = 256) ----------
  constexpr int NF2 = F_OUT / 32;
  f32x4 acc2[2][NF2];
  #pragma unroll
  for (int am = 0; am < 2; am++)
    #pragma unroll
    for (int nf = 0; nf < NF2; nf++) acc2[am][nf] = f32x4{0.f, 0.f, 0.f, 0.f};

  for (int ks = 0; ks < 256; ks += 32) {
    __syncthreads();                           // covers aggL writes on first iter
    if (tid < F_OUT * 2) {
      int fo = tid >> 1, half = tid & 1;       // stage Hs[fo][0..31] = WT[fo][ks..+31]
      const int4* src = (const int4*)(WT + fo * 256 + ks + (half << 4));
      int4 v0 = src[0], v1 = src[1];
      *(int4*)&Hs[fo][half << 4] = v0;
      *(int4*)&Hs[fo][(half << 4) + 8] = v1;
    }
    __syncthreads();
    int rg = (wm << 1) + (ks >> 7);            // which wave's aggL holds this fin-half
    int ko = (ks & 127) + (l4 << 3);
    bf16x8 af0 = *(const bf16x8*)&aggL[rg][l15][ko];
    bf16x8 af1 = *(const bf16x8*)&aggL[rg][16 + l15][ko];
    #pragma unroll
    for (int nf = 0; nf < NF2; nf++) {
      bf16x8 bv = *(const bf16x8*)&Hs[wn * (F_OUT / 2) + (nf << 4) + l15][l4 << 3];
      acc2[0][nf] = __builtin_amdgcn_mfma_f32_16x16x32_bf16(af0, bv, acc2[0][nf], 0, 0, 0);
      acc2[1][nf] = __builtin_amdgcn_mfma_f32_16x16x32_bf16(af1, bv, acc2[1][nf], 0, 0, 0);
    }
  }

  // epilogue: bias + relu + store
  #pragma unroll
  for (int am = 0; am < 2; am++) {
    int node0 = rowbase + (am << 4) + (l4 << 2);
    #pragma unroll
    for (int nf = 0; nf < NF2; nf++) {
      int fo = wn * (F_OUT / 2) + (nf << 4) + l15;
      float bb = bias[fo];
      float v0 = fmaxf(acc2[am][nf][0] + bb, 0.f);
      float v1 = fmaxf(acc2[am][nf][1] + bb, 0.f);
      float v2 = fmaxf(acc2[am][nf][2] + bb, 0.f);
      float v3 = fmaxf(acc2[am][nf][3] + bb, 0.f);
      if (!FINAL) {
        ushort4 p;
        p.x = (unsigned short)f2bf(v0); p.y = (unsigned short)f2bf(v1);
        p.z = (unsigned short)f2bf(v2); p.w = (unsigned short)f2bf(v3);
        *(ushort4*)(HTout + ((size_t)bw * F_OUT + fo) * NN + node0) = p;
      } else {
        float* ob = Out + ((size_t)bw * NN + node0) * F_OUT + fo;
        ob[0]         = v0;
        ob[F_OUT]     = v1;
        ob[2 * F_OUT] = v2;
        ob[3 * F_OUT] = v3;
      }
    }
  }
}

extern "C" void kernel_launch(void* const* d_in, const int* in_sizes, int n_in,
                              void* d_out, int out_size, void* d_ws, size_t ws_size,
                              hipStream_t stream) {
  const float* X   = (const float*)d_in[0];
  const float* adj = (const float*)d_in[1];
  const float* W1  = (const float*)d_in[2];
  const float* b1  = (const float*)d_in[3];
  const float* W2  = (const float*)d_in[4];
  const float* b2  = (const float*)d_in[5];
  const float* W3  = (const float*)d_in[6];
  const float* b3  = (const float*)d_in[7];
  float* out = (float*)d_out;

  char* ws = (char*)d_ws;
  float* dinv = (float*)ws;                              // 128 KB
  short* WT1  = (short*)(ws + 131072);                   // 128 KB
  short* WT2  = (short*)(ws + 262144);                   // 128 KB
  short* WT3  = (short*)(ws + 393216);                   //  64 KB
  short* bufA = (short*)(ws + 458752);                   //  16 MB
  short* bufB = (short*)(ws + 458752 + 16777216);        //  16 MB

  compute_dinv<<<8192, 256, 0, stream>>>(adj, dinv);
  transpose_x<<<dim3(16, 4, 32), 256, 0, stream>>>(X, bufA);
  transpose_w<<<256, 256, 0, stream>>>(W1, WT1, 256);
  transpose_w<<<256, 256, 0, stream>>>(W2, WT2, 256);
  transpose_w<<<128, 256, 0, stream>>>(W3, WT3, 128);

  gcn_layer<256, false><<<256, 512, 0, stream>>>(adj, dinv, bufA, WT1, b1, bufB, nullptr);
  gcn_layer<256, false><<<256, 512, 0, stream>>>(adj, dinv, bufB, WT2, b2, bufA, nullptr);
  gcn_layer<128, true ><<<256, 512, 0, stream>>>(adj, dinv, bufA, WT3, b3, nullptr, out);
}

// Round 2
// 224.447 us; speedup vs baseline: 1.1608x; 1.1608x over previous
//
#include <hip/hip_runtime.h>
#include <hip/hip_bf16.h>
#include <cstdint>
#include <cstddef>

#define NN 1024
#define FF 256

typedef __attribute__((ext_vector_type(8))) short bf16x8;
typedef __attribute__((ext_vector_type(4))) float f32x4;

typedef __attribute__((address_space(1))) const void* gas_ptr;
typedef __attribute__((address_space(3))) void* las_ptr;

__device__ __forceinline__ short f2bf(float x) {
  unsigned int u = __float_as_uint(x);
  u = (u + 0x7fffu + ((u >> 16) & 1u)) >> 16;   // RNE
  return (short)u;
}

__device__ __forceinline__ void gload_lds16(const void* g, void* l) {
  __builtin_amdgcn_global_load_lds((gas_ptr)g, (las_ptr)l, 16, 0, 0);
}

// ---------------- d = (rowsum(adj)+1)^-1/2, one wave per row ----------------
__global__ __launch_bounds__(256)
void compute_dinv(const float* __restrict__ adj, float* __restrict__ dinv) {
  int wid = threadIdx.x >> 6, lane = threadIdx.x & 63;
  int row = (blockIdx.x << 2) + wid;           // 0..32767
  const float4* r = (const float4*)(adj + (size_t)row * NN);
  float s = 0.f;
  #pragma unroll
  for (int i = 0; i < 4; i++) {
    float4 v = r[lane + (i << 6)];
    s += (v.x + v.y) + (v.z + v.w);
  }
  #pragma unroll
  for (int off = 32; off > 0; off >>= 1) s += __shfl_down(s, off, 64);
  if (lane == 0) dinv[row] = rsqrtf(s + 1.0f);
}

// -------- Anorm[bw][r][k] bf16 = (adj + I) * dr * dk  (one block per row) ---
__global__ __launch_bounds__(256)
void normalize_adj(const float* __restrict__ adj, const float* __restrict__ dinv,
                   short* __restrict__ Anorm) {
  int gid = blockIdx.x;                        // bw*1024 + r
  int bw = gid >> 10, r = gid & 1023;
  float dr = dinv[gid];
  const float* src = adj + (size_t)gid * NN;
  const float* dv  = dinv + (bw << 10);
  int k = threadIdx.x << 2;
  float4 a = *(const float4*)(src + k);
  float4 d = *(const float4*)(dv + k);
  float v0 = (a.x + ((r == k + 0) ? 1.f : 0.f)) * dr * d.x;
  float v1 = (a.y + ((r == k + 1) ? 1.f : 0.f)) * dr * d.y;
  float v2 = (a.z + ((r == k + 2) ? 1.f : 0.f)) * dr * d.z;
  float v3 = (a.w + ((r == k + 3) ? 1.f : 0.f)) * dr * d.w;
  ushort4 o;
  o.x = (unsigned short)f2bf(v0); o.y = (unsigned short)f2bf(v1);
  o.z = (unsigned short)f2bf(v2); o.w = (unsigned short)f2bf(v3);
  *(ushort4*)(Anorm + (size_t)gid * NN + k) = o;
}

// ---------------- X [bw][n][256] fp32 -> XT [bw][256][1024] bf16 ------------
__global__ __launch_bounds__(256)
void transpose_x(const float* __restrict__ X, short* __restrict__ XT) {
  __shared__ short T[64][72];
  int bwo = blockIdx.z;
  int n0 = blockIdx.x << 6, f0 = blockIdx.y << 6;
  int t = threadIdx.x;
  {
    int n = t >> 2, fc = (t & 3) << 4;
    const float* src = X + (((size_t)bwo * NN + n0 + n) * FF) + f0 + fc;
    #pragma unroll
    for (int i = 0; i < 4; i++) {
      float4 v = ((const float4*)src)[i];
      ushort4 p;
      p.x = (unsigned short)f2bf(v.x); p.y = (unsigned short)f2bf(v.y);
      p.z = (unsigned short)f2bf(v.z); p.w = (unsigned short)f2bf(v.w);
      *(ushort4*)&T[n][fc + (i << 2)] = p;
    }
  }
  __syncthreads();
  {
    int f = t >> 2, nc = (t & 3) << 4;
    short* dst = XT + (((size_t)bwo * FF + f0 + f) * NN) + n0 + nc;
    short tmp[16];
    #pragma unroll
    for (int i = 0; i < 16; i++) tmp[i] = T[nc + i][f];
    *(int4*)dst = *(int4*)&tmp[0];
    *(int4*)(dst + 8) = *(int4*)&tmp[8];
  }
}

// ---------------- W [256][FO] fp32 -> WT [FO][256] bf16 ---------------------
__global__ __launch_bounds__(256)
void transpose_w(const float* __restrict__ W, short* __restrict__ WT, int FO) {
  int idx = blockIdx.x * 256 + threadIdx.x;
  if (idx >= FO * 256) return;
  int fo = idx >> 8, fi = idx & 255;
  WT[idx] = f2bf(W[fi * FO + fo]);
}

// ---------------- fused layer ----------------------------------------------
// Block: 512 thr (8 waves, 4M x 2N), tile 128 rows x 256 cols, grid 256.
// Stage1: agg = Anorm @ H; B (HT) double-buffered in LDS via global_load_lds
// (swizzled source, counted vmcnt(4)); A direct from global bf16.
// Stage2: out = relu(agg @ W + b); agg spilled once to LDS; W from L2 direct.
template<int F_OUT, bool FINAL, bool PRE>
__global__ __launch_bounds__(512, 2)
void gcn_layer(const short* __restrict__ Anorm,   // [32][1024][1024] bf16 (PRE)
               const float* __restrict__ adj,     // fallback
               const float* __restrict__ dinv,    // fallback
               const short* __restrict__ HTin,    // [32][256][1024] bf16
               const short* __restrict__ WT,      // [F_OUT][256] bf16
               const float* __restrict__ bias,
               short* __restrict__ HTout,         // [32][F_OUT][1024] bf16
               float* __restrict__ Out) {         // [32][1024][F_OUT] fp32
  constexpr int NF2 = F_OUT / 32;
  __shared__ __align__(16) char lds[67584];       // B dbuf 2x32KB, then aggL 128x264

  int b = blockIdx.x;
  int bw = ((b & 7) << 2) + ((b >> 3) & 3);       // same-bw blocks share an XCD
  int rb = b >> 5;
  int r0 = rb << 7;

  int tid = threadIdx.x;
  int wid = tid >> 6, lane = tid & 63;
  int l15 = lane & 15, l4 = lane >> 4;
  int wm = wid >> 1, wn = wid & 1;

  const short* HTb = HTin + (size_t)bw * FF * NN;
  int rowA = r0 + (wm << 5) + l15;

  const short* aB = nullptr;
  const float* adjB = nullptr; const float* dvB = nullptr;
  float dr0 = 0.f, dr1 = 0.f;
  if constexpr (PRE) {
    aB = Anorm + (((size_t)bw << 10) + rowA) * NN + (l4 << 3);
  } else {
    adjB = adj + (size_t)bw * NN * NN;
    dvB  = dinv + (bw << 10);
    dr0 = dvB[rowA]; dr1 = dvB[rowA + 16];
  }

  f32x4 acc[2][8];
  #pragma unroll
  for (int am = 0; am < 2; am++)
    #pragma unroll
    for (int nf = 0; nf < 8; nf++) acc[am][nf] = f32x4{0.f, 0.f, 0.f, 0.f};

  // stage HT tile [256 f][64 k] into buffer bufsel; source XOR-swizzled so
  // the linear global_load_lds fill yields the bank-conflict-free layout.
  auto stage = [&](int bufsel, int k0) {
    char* base = lds + (bufsel << 15);
    #pragma unroll
    for (int i = 0; i < 4; i++) {
      int s = (i << 9) + tid;                    // slot 0..2047
      int f = s >> 3, u = s & 7;
      const short* g = HTb + (size_t)f * NN + k0 + ((u ^ (f & 7)) << 3);
      gload_lds16(g, base + (((i << 9) + (wid << 6)) << 4));
    }
  };

  stage(0, 0);

  for (int t = 0; t < 16; t++) {
    int k0 = t << 6;
    // ---- A fragments (direct global) ----
    bf16x8 a[2][2];
    if constexpr (PRE) {
      #pragma unroll
      for (int am = 0; am < 2; am++)
        #pragma unroll
        for (int kt = 0; kt < 2; kt++)
          a[am][kt] = *(const bf16x8*)(aB + (size_t)(am << 4) * NN + k0 + (kt << 5));
    } else {
      #pragma unroll
      for (int kt = 0; kt < 2; kt++) {
        int kk = k0 + (kt << 5) + (l4 << 3);
        float4 d0 = *(const float4*)(dvB + kk), d1 = *(const float4*)(dvB + kk + 4);
        float dk[8] = {d0.x,d0.y,d0.z,d0.w,d1.x,d1.y,d1.z,d1.w};
        #pragma unroll
        for (int am = 0; am < 2; am++) {
          int row = rowA + (am << 4);
          float dr = am ? dr1 : dr0;
          const float* ap = adjB + (size_t)row * NN + kk;
          float4 a0 = *(const float4*)ap, a1 = *(const float4*)(ap + 4);
          float av[8] = {a0.x,a0.y,a0.z,a0.w,a1.x,a1.y,a1.z,a1.w};
          union { short s[8]; bf16x8 v; } pk;
          #pragma unroll
          for (int j = 0; j < 8; j++)
            pk.s[j] = f2bf((av[j] + ((row == kk + j) ? 1.f : 0.f)) * dr * dk[j]);
          a[am][kt] = pk.v;
        }
      }
    }
    // ---- prefetch next B tile, keep it in flight across the barrier ----
    if (t < 15) stage((t + 1) & 1, k0 + 64);
    asm volatile("s_waitcnt vmcnt(4)" ::: "memory");   // current tile + A drained
    __builtin_amdgcn_sched_barrier(0);
    __builtin_amdgcn_s_barrier();
    const char* bb = lds + ((size_t)(t & 1) << 15);
    #pragma unroll
    for (int kt = 0; kt < 2; kt++)
      #pragma unroll
      for (int nf = 0; nf < 8; nf++) {
        int f = (wn << 7) + (nf << 4) + l15;
        int u = ((kt << 2) + l4) ^ (l15 & 7);
        bf16x8 bv = *(const bf16x8*)(bb + f * 128 + (u << 4));
        acc[0][nf] = __builtin_amdgcn_mfma_f32_16x16x32_bf16(a[0][kt], bv, acc[0][nf], 0, 0, 0);
        acc[1][nf] = __builtin_amdgcn_mfma_f32_16x16x32_bf16(a[1][kt], bv, acc[1][nf], 0, 0, 0);
      }
    __builtin_amdgcn_sched_barrier(0);
    __builtin_amdgcn_s_barrier();                // reads done before next overwrite
  }

  // ---- spill agg (bf16) to LDS, reusing the B-buffer space ----
  short* aggL = (short*)lds;                     // [128][264]
  #pragma unroll
  for (int am = 0; am < 2; am++)
    #pragma unroll
    for (int nf = 0; nf < 8; nf++)
      #pragma unroll
      for (int j = 0; j < 4; j++)
        aggL[(size_t)((wm << 5) + (am << 4) + (l4 << 2) + j) * 264 +
             (wn << 7) + (nf << 4) + l15] = f2bf(acc[am][nf][j]);
  asm volatile("s_waitcnt lgkmcnt(0)" ::: "memory");
  __builtin_amdgcn_sched_barrier(0);
  __builtin_amdgcn_s_barrier();

  // ---- stage 2: barrier-free, W fragments straight from L2 ----
  f32x4 acc2[2][NF2];
  #pragma unroll
  for (int am = 0; am < 2; am++)
    #pragma unroll
    for (int nf = 0; nf < NF2; nf++) acc2[am][nf] = f32x4{0.f, 0.f, 0.f, 0.f};

  #pragma unroll
  for (int ks = 0; ks < 8; ks++) {
    int kk = (ks << 5) + (l4 << 3);
    bf16x8 a0 = *(const bf16x8*)(aggL + (size_t)((wm << 5) + l15) * 264 + kk);
    bf16x8 a1 = *(const bf16x8*)(aggL + (size_t)((wm << 5) + 16 + l15) * 264 + kk);
    #pragma unroll
    for (int nf = 0; nf < NF2; nf++) {
      int fo = wn * (F_OUT / 2) + (nf << 4) + l15;
      bf16x8 bv = *(const bf16x8*)(WT + fo * 256 + kk);
      acc2[0][nf] = __builtin_amdgcn_mfma_f32_16x16x32_bf16(a0, bv, acc2[0][nf], 0, 0, 0);
      acc2[1][nf] = __builtin_amdgcn_mfma_f32_16x16x32_bf16(a1, bv, acc2[1][nf], 0, 0, 0);
    }
  }

  // ---- epilogue: bias + relu + store ----
  #pragma unroll
  for (int am = 0; am < 2; am++) {
    int node0 = r0 + (wm << 5) + (am << 4) + (l4 << 2);
    #pragma unroll
    for (int nf = 0; nf < NF2; nf++) {
      int fo = wn * (F_OUT / 2) + (nf << 4) + l15;
      float bb = bias[fo];
      float v0 = fmaxf(acc2[am][nf][0] + bb, 0.f);
      float v1 = fmaxf(acc2[am][nf][1] + bb, 0.f);
      float v2 = fmaxf(acc2[am][nf][2] + bb, 0.f);
      float v3 = fmaxf(acc2[am][nf][3] + bb, 0.f);
      if (!FINAL) {
        ushort4 p;
        p.x = (unsigned short)f2bf(v0); p.y = (unsigned short)f2bf(v1);
        p.z = (unsigned short)f2bf(v2); p.w = (unsigned short)f2bf(v3);
        *(ushort4*)(HTout + ((size_t)bw * F_OUT + fo) * NN + node0) = p;
      } else {
        float* ob = Out + ((size_t)bw * NN + node0) * F_OUT + fo;
        ob[0]         = v0;
        ob[F_OUT]     = v1;
        ob[2 * F_OUT] = v2;
        ob[3 * F_OUT] = v3;
      }
    }
  }
}

extern "C" void kernel_launch(void* const* d_in, const int* in_sizes, int n_in,
                              void* d_out, int out_size, void* d_ws, size_t ws_size,
                              hipStream_t stream) {
  const float* X   = (const float*)d_in[0];
  const float* adj = (const float*)d_in[1];
  const float* W1  = (const float*)d_in[2];
  const float* b1  = (const float*)d_in[3];
  const float* W2  = (const float*)d_in[4];
  const float* b2  = (const float*)d_in[5];
  const float* W3  = (const float*)d_in[6];
  const float* b3  = (const float*)d_in[7];
  float* out = (float*)d_out;

  char* ws = (char*)d_ws;
  float* dinv = (float*)ws;                              // 128 KB
  short* WT1  = (short*)(ws + 131072);                   // 128 KB
  short* WT2  = (short*)(ws + 262144);                   // 128 KB
  short* WT3  = (short*)(ws + 393216);                   //  64 KB
  short* bufA = (short*)(ws + 458752);                   //  16 MB
  short* bufB = (short*)(ws + 458752 + 16777216);        //  16 MB
  short* Anorm = (short*)(ws + 458752 + 2 * 16777216);   //  64 MB
  const size_t need = 458752ull + 2ull * 16777216ull + 67108864ull;
  bool pre = ws_size >= need;

  compute_dinv<<<8192, 256, 0, stream>>>(adj, dinv);
  if (pre) normalize_adj<<<32768, 256, 0, stream>>>(adj, dinv, Anorm);
  transpose_x<<<dim3(16, 4, 32), 256, 0, stream>>>(X, bufA);
  transpose_w<<<256, 256, 0, stream>>>(W1, WT1, 256);
  transpose_w<<<256, 256, 0, stream>>>(W2, WT2, 256);
  transpose_w<<<128, 256, 0, stream>>>(W3, WT3, 128);

  if (pre) {
    gcn_layer<256, false, true><<<256, 512, 0, stream>>>(Anorm, adj, dinv, bufA, WT1, b1, bufB, nullptr);
    gcn_layer<256, false, true><<<256, 512, 0, stream>>>(Anorm, adj, dinv, bufB, WT2, b2, bufA, nullptr);
    gcn_layer<128, true,  true><<<256, 512, 0, stream>>>(Anorm, adj, dinv, bufA, WT3, b3, nullptr, out);
  } else {
    gcn_layer<256, false, false><<<256, 512, 0, stream>>>(nullptr, adj, dinv, bufA, WT1, b1, bufB, nullptr);
    gcn_layer<256, false, false><<<256, 512, 0, stream>>>(nullptr, adj, dinv, bufB, WT2, b2, bufA, nullptr);
    gcn_layer<128, true,  false><<<256, 512, 0, stream>>>(nullptr, adj, dinv, bufA, WT3, b3, nullptr, out);
  }
}

// Round 3
// 211.957 us; speedup vs baseline: 1.2292x; 1.0589x over previous
//
#include <hip/hip_runtime.h>
#include <hip/hip_bf16.h>
#include <cstdint>
#include <cstddef>

#define NN 1024
#define FF 256

typedef __attribute__((ext_vector_type(8))) short bf16x8;
typedef __attribute__((ext_vector_type(4))) float f32x4;

typedef __attribute__((address_space(1))) const void* gas_ptr;
typedef __attribute__((address_space(3))) void* las_ptr;

__device__ __forceinline__ short f2bf(float x) {
  unsigned int u = __float_as_uint(x);
  u = (u + 0x7fffu + ((u >> 16) & 1u)) >> 16;   // RNE
  return (short)u;
}

__device__ __forceinline__ void gload_lds16(const void* g, void* l) {
  __builtin_amdgcn_global_load_lds((gas_ptr)g, (las_ptr)l, 16, 0, 0);
}

// ---------------- d = (rowsum(adj)+1)^-1/2, one wave per row ----------------
__global__ __launch_bounds__(256)
void compute_dinv(const float* __restrict__ adj, float* __restrict__ dinv) {
  int wid = threadIdx.x >> 6, lane = threadIdx.x & 63;
  int row = (blockIdx.x << 2) + wid;           // 0..32767
  const float4* r = (const float4*)(adj + (size_t)row * NN);
  float s = 0.f;
  #pragma unroll
  for (int i = 0; i < 4; i++) {
    float4 v = r[lane + (i << 6)];
    s += (v.x + v.y) + (v.z + v.w);
  }
  #pragma unroll
  for (int off = 32; off > 0; off >>= 1) s += __shfl_down(s, off, 64);
  if (lane == 0) dinv[row] = rsqrtf(s + 1.0f);
}

// -------- Anorm[bw][r][k] bf16 = (adj + I) * dr * dk  (one block per row) ---
__global__ __launch_bounds__(256)
void normalize_adj(const float* __restrict__ adj, const float* __restrict__ dinv,
                   short* __restrict__ Anorm) {
  int gid = blockIdx.x;                        // bw*1024 + r
  int bw = gid >> 10, r = gid & 1023;
  float dr = dinv[gid];
  const float* src = adj + (size_t)gid * NN;
  const float* dv  = dinv + (bw << 10);
  int k = threadIdx.x << 2;
  float4 a = *(const float4*)(src + k);
  float4 d = *(const float4*)(dv + k);
  float v0 = (a.x + ((r == k + 0) ? 1.f : 0.f)) * dr * d.x;
  float v1 = (a.y + ((r == k + 1) ? 1.f : 0.f)) * dr * d.y;
  float v2 = (a.z + ((r == k + 2) ? 1.f : 0.f)) * dr * d.z;
  float v3 = (a.w + ((r == k + 3) ? 1.f : 0.f)) * dr * d.w;
  ushort4 o;
  o.x = (unsigned short)f2bf(v0); o.y = (unsigned short)f2bf(v1);
  o.z = (unsigned short)f2bf(v2); o.w = (unsigned short)f2bf(v3);
  *(ushort4*)(Anorm + (size_t)gid * NN + k) = o;
}

// ---------------- X [bw][n][256] fp32 -> XT [bw][256][1024] bf16 ------------
__global__ __launch_bounds__(256)
void transpose_x(const float* __restrict__ X, short* __restrict__ XT) {
  __shared__ short T[64][72];
  int bwo = blockIdx.z;
  int n0 = blockIdx.x << 6, f0 = blockIdx.y << 6;
  int t = threadIdx.x;
  {
    int n = t >> 2, fc = (t & 3) << 4;
    const float* src = X + (((size_t)bwo * NN + n0 + n) * FF) + f0 + fc;
    #pragma unroll
    for (int i = 0; i < 4; i++) {
      float4 v = ((const float4*)src)[i];
      ushort4 p;
      p.x = (unsigned short)f2bf(v.x); p.y = (unsigned short)f2bf(v.y);
      p.z = (unsigned short)f2bf(v.z); p.w = (unsigned short)f2bf(v.w);
      *(ushort4*)&T[n][fc + (i << 2)] = p;
    }
  }
  __syncthreads();
  {
    int f = t >> 2, nc = (t & 3) << 4;
    short* dst = XT + (((size_t)bwo * FF + f0 + f) * NN) + n0 + nc;
    short tmp[16];
    #pragma unroll
    for (int i = 0; i < 16; i++) tmp[i] = T[nc + i][f];
    *(int4*)dst = *(int4*)&tmp[0];
    *(int4*)(dst + 8) = *(int4*)&tmp[8];
  }
}

// ---------------- W [256][FO] fp32 -> WT [FO][256] bf16 ---------------------
__global__ __launch_bounds__(256)
void transpose_w(const float* __restrict__ W, short* __restrict__ WT, int FO) {
  int idx = blockIdx.x * 256 + threadIdx.x;
  if (idx >= FO * 256) return;
  int fo = idx >> 8, fi = idx & 255;
  WT[idx] = f2bf(W[fi * FO + fo]);
}

// ---------------- fused layer ----------------------------------------------
// Grid 512 x 256 thr (4 waves, 2M x 2N), tile 64 rows x 256 cols, 2 blocks/CU.
// Pipeline: A reg-prefetch 1 tile ahead + B gload_lds 1 tile ahead, counted
// vmcnt(12) so next-tile loads stay in flight across the barrier.
template<int F_OUT, bool FINAL, bool PRE>
__global__ __launch_bounds__(256)
void gcn_layer(const short* __restrict__ Anorm,   // [32][1024][1024] bf16 (PRE)
               const float* __restrict__ adj,     // fallback
               const float* __restrict__ dinv,    // fallback
               const short* __restrict__ HTin,    // [32][256][1024] bf16
               const short* __restrict__ WT,      // [F_OUT][256] bf16
               const float* __restrict__ bias,
               short* __restrict__ HTout,         // [32][F_OUT][1024] bf16
               float* __restrict__ Out) {         // [32][1024][F_OUT] fp32
  constexpr int NF2 = F_OUT / 32;
  __shared__ __align__(16) char lds[65536];       // B dbuf 2x32KB; aggL reuses

  int b = blockIdx.x;
  int bw = ((b & 7) << 2) + ((b >> 3) & 3);       // same-bw blocks share an XCD
  int rb = b >> 5;                                // 0..15
  int r0 = rb << 6;                               // 64 rows / block

  int tid = threadIdx.x;
  int wid = tid >> 6, lane = tid & 63;
  int l15 = lane & 15, l4 = lane >> 4;
  int wm = wid >> 1, wn = wid & 1;

  const short* HTb = HTin + (size_t)bw * FF * NN;
  int rowA = r0 + (wm << 5) + l15;

  const short* aB = nullptr;
  const float* adjB = nullptr; const float* dvB = nullptr;
  float dr0 = 0.f, dr1 = 0.f;
  if constexpr (PRE) {
    aB = Anorm + (((size_t)bw << 10) + rowA) * NN + (l4 << 3);
  } else {
    adjB = adj + (size_t)bw * NN * NN;
    dvB  = dinv + (bw << 10);
    dr0 = dvB[rowA]; dr1 = dvB[rowA + 16];
  }

  f32x4 acc[2][8];
  #pragma unroll
  for (int am = 0; am < 2; am++)
    #pragma unroll
    for (int nf = 0; nf < 8; nf++) acc[am][nf] = f32x4{0.f, 0.f, 0.f, 0.f};

  // stage HT tile [256 f][64 k] -> LDS buffer; linear dest, XOR-swizzled src.
  auto stage = [&](int bufsel, int k0) {
    char* base = lds + (bufsel << 15);
    #pragma unroll
    for (int i = 0; i < 8; i++) {
      int s = (i << 8) + tid;                    // slot 0..2047
      int f = s >> 3, u = s & 7;
      const short* g = HTb + (size_t)f * NN + k0 + ((u ^ (f & 7)) << 3);
      gload_lds16(g, base + (s << 4));
    }
  };

  auto loadA = [&](bf16x8 (&dst)[2][2], int k0) {
    if constexpr (PRE) {
      #pragma unroll
      for (int am = 0; am < 2; am++)
        #pragma unroll
        for (int kt = 0; kt < 2; kt++)
          dst[am][kt] = *(const bf16x8*)(aB + (size_t)(am << 4) * NN + k0 + (kt << 5));
    } else {
      #pragma unroll
      for (int kt = 0; kt < 2; kt++) {
        int kk = k0 + (kt << 5) + (l4 << 3);
        float4 d0 = *(const float4*)(dvB + kk), d1 = *(const float4*)(dvB + kk + 4);
        float dk[8] = {d0.x,d0.y,d0.z,d0.w,d1.x,d1.y,d1.z,d1.w};
        #pragma unroll
        for (int am = 0; am < 2; am++) {
          int row = rowA + (am << 4);
          float dr = am ? dr1 : dr0;
          const float* ap = adjB + (size_t)row * NN + kk;
          float4 a0 = *(const float4*)ap, a1 = *(const float4*)(ap + 4);
          float av[8] = {a0.x,a0.y,a0.z,a0.w,a1.x,a1.y,a1.z,a1.w};
          union { short s[8]; bf16x8 v; } pk;
          #pragma unroll
          for (int j = 0; j < 8; j++)
            pk.s[j] = f2bf((av[j] + ((row == kk + j) ? 1.f : 0.f)) * dr * dk[j]);
          dst[am][kt] = pk.v;
        }
      }
    }
  };

  auto mfmaBlock = [&](bf16x8 (&a)[2][2], int parity) {
    const char* bb = lds + (parity << 15);
    __builtin_amdgcn_s_setprio(1);
    #pragma unroll
    for (int kt = 0; kt < 2; kt++)
      #pragma unroll
      for (int nf = 0; nf < 8; nf++) {
        int f = (wn << 7) + (nf << 4) + l15;
        int qg = (kt << 2) + l4;
        bf16x8 bv = *(const bf16x8*)(bb + f * 128 + ((qg ^ (f & 7)) << 4));
        acc[0][nf] = __builtin_amdgcn_mfma_f32_16x16x32_bf16(a[0][kt], bv, acc[0][nf], 0, 0, 0);
        acc[1][nf] = __builtin_amdgcn_mfma_f32_16x16x32_bf16(a[1][kt], bv, acc[1][nf], 0, 0, 0);
      }
    __builtin_amdgcn_s_setprio(0);
  };

  bf16x8 aA[2][2], aBuf[2][2];

  stage(0, 0);
  if constexpr (PRE) loadA(aA, 0);

#define STEP(ACUR, ANXT, T, ILAST)                                            \
  {                                                                           \
    if constexpr (PRE) { if (!(ILAST)) loadA(ANXT, ((T) + 1) << 6); }         \
    else loadA(ACUR, (T) << 6);                                               \
    if (!(ILAST)) stage(((T) + 1) & 1, ((T) + 1) << 6);                       \
    if (ILAST) { asm volatile("s_waitcnt vmcnt(0)" ::: "memory"); }           \
    else if constexpr (PRE) { asm volatile("s_waitcnt vmcnt(12)" ::: "memory"); } \
    else { asm volatile("s_waitcnt vmcnt(8)" ::: "memory"); }                 \
    __builtin_amdgcn_sched_barrier(0);                                        \
    __builtin_amdgcn_s_barrier();                                             \
    mfmaBlock(ACUR, (T) & 1);                                                 \
    if (!(ILAST)) {                                                           \
      asm volatile("s_waitcnt lgkmcnt(0)" ::: "memory");                      \
      __builtin_amdgcn_sched_barrier(0);                                      \
      __builtin_amdgcn_s_barrier();                                           \
    }                                                                         \
  }

  for (int it = 0; it < 7; ++it) {
    STEP(aA, aBuf, 2 * it, false);
    STEP(aBuf, aA, 2 * it + 1, false);
  }
  STEP(aA, aBuf, 14, false);
  STEP(aBuf, aA, 15, true);
#undef STEP

  // all waves done reading buf1 before aggL (overlaps it) is written
  asm volatile("s_waitcnt lgkmcnt(0)" ::: "memory");
  __builtin_amdgcn_sched_barrier(0);
  __builtin_amdgcn_s_barrier();

  // ---- spill agg (bf16) to LDS ----
  short* aggL = (short*)lds;                     // [64][264]
  #pragma unroll
  for (int am = 0; am < 2; am++)
    #pragma unroll
    for (int nf = 0; nf < 8; nf++)
      #pragma unroll
      for (int j = 0; j < 4; j++)
        aggL[(size_t)((wm << 5) + (am << 4) + (l4 << 2) + j) * 264 +
             (wn << 7) + (nf << 4) + l15] = f2bf(acc[am][nf][j]);
  asm volatile("s_waitcnt lgkmcnt(0)" ::: "memory");
  __builtin_amdgcn_sched_barrier(0);
  __builtin_amdgcn_s_barrier();

  // ---- stage 2: barrier-free, W fragments straight from L2 ----
  f32x4 acc2[2][NF2];
  #pragma unroll
  for (int am = 0; am < 2; am++)
    #pragma unroll
    for (int nf = 0; nf < NF2; nf++) acc2[am][nf] = f32x4{0.f, 0.f, 0.f, 0.f};

  #pragma unroll
  for (int ks = 0; ks < 8; ks++) {
    int kk = (ks << 5) + (l4 << 3);
    bf16x8 a0 = *(const bf16x8*)(aggL + (size_t)((wm << 5) + l15) * 264 + kk);
    bf16x8 a1 = *(const bf16x8*)(aggL + (size_t)((wm << 5) + 16 + l15) * 264 + kk);
    #pragma unroll
    for (int nf = 0; nf < NF2; nf++) {
      int fo = wn * (F_OUT / 2) + (nf << 4) + l15;
      bf16x8 bv = *(const bf16x8*)(WT + fo * 256 + kk);
      acc2[0][nf] = __builtin_amdgcn_mfma_f32_16x16x32_bf16(a0, bv, acc2[0][nf], 0, 0, 0);
      acc2[1][nf] = __builtin_amdgcn_mfma_f32_16x16x32_bf16(a1, bv, acc2[1][nf], 0, 0, 0);
    }
  }

  // ---- epilogue: bias + relu + store ----
  #pragma unroll
  for (int am = 0; am < 2; am++) {
    int node0 = r0 + (wm << 5) + (am << 4) + (l4 << 2);
    #pragma unroll
    for (int nf = 0; nf < NF2; nf++) {
      int fo = wn * (F_OUT / 2) + (nf << 4) + l15;
      float bb = bias[fo];
      float v0 = fmaxf(acc2[am][nf][0] + bb, 0.f);
      float v1 = fmaxf(acc2[am][nf][1] + bb, 0.f);
      float v2 = fmaxf(acc2[am][nf][2] + bb, 0.f);
      float v3 = fmaxf(acc2[am][nf][3] + bb, 0.f);
      if (!FINAL) {
        ushort4 p;
        p.x = (unsigned short)f2bf(v0); p.y = (unsigned short)f2bf(v1);
        p.z = (unsigned short)f2bf(v2); p.w = (unsigned short)f2bf(v3);
        *(ushort4*)(HTout + ((size_t)bw * F_OUT + fo) * NN + node0) = p;
      } else {
        float* ob = Out + ((size_t)bw * NN + node0) * F_OUT + fo;
        ob[0]         = v0;
        ob[F_OUT]     = v1;
        ob[2 * F_OUT] = v2;
        ob[3 * F_OUT] = v3;
      }
    }
  }
}

extern "C" void kernel_launch(void* const* d_in, const int* in_sizes, int n_in,
                              void* d_out, int out_size, void* d_ws, size_t ws_size,
                              hipStream_t stream) {
  const float* X   = (const float*)d_in[0];
  const float* adj = (const float*)d_in[1];
  const float* W1  = (const float*)d_in[2];
  const float* b1  = (const float*)d_in[3];
  const float* W2  = (const float*)d_in[4];
  const float* b2  = (const float*)d_in[5];
  const float* W3  = (const float*)d_in[6];
  const float* b3  = (const float*)d_in[7];
  float* out = (float*)d_out;

  char* ws = (char*)d_ws;
  float* dinv = (float*)ws;                              // 128 KB
  short* WT1  = (short*)(ws + 131072);                   // 128 KB
  short* WT2  = (short*)(ws + 262144);                   // 128 KB
  short* WT3  = (short*)(ws + 393216);                   //  64 KB
  short* bufA = (short*)(ws + 458752);                   //  16 MB
  short* bufB = (short*)(ws + 458752 + 16777216);        //  16 MB
  short* Anorm = (short*)(ws + 458752 + 2 * 16777216);   //  64 MB
  const size_t need = 458752ull + 2ull * 16777216ull + 67108864ull;
  bool pre = ws_size >= need;

  compute_dinv<<<8192, 256, 0, stream>>>(adj, dinv);
  if (pre) normalize_adj<<<32768, 256, 0, stream>>>(adj, dinv, Anorm);
  transpose_x<<<dim3(16, 4, 32), 256, 0, stream>>>(X, bufA);
  transpose_w<<<256, 256, 0, stream>>>(W1, WT1, 256);
  transpose_w<<<256, 256, 0, stream>>>(W2, WT2, 256);
  transpose_w<<<128, 256, 0, stream>>>(W3, WT3, 128);

  if (pre) {
    gcn_layer<256, false, true><<<512, 256, 0, stream>>>(Anorm, adj, dinv, bufA, WT1, b1, bufB, nullptr);
    gcn_layer<256, false, true><<<512, 256, 0, stream>>>(Anorm, adj, dinv, bufB, WT2, b2, bufA, nullptr);
    gcn_layer<128, true,  true><<<512, 256, 0, stream>>>(Anorm, adj, dinv, bufA, WT3, b3, nullptr, out);
  } else {
    gcn_layer<256, false, false><<<512, 256, 0, stream>>>(nullptr, adj, dinv, bufA, WT1, b1, bufB, nullptr);
    gcn_layer<256, false, false><<<512, 256, 0, stream>>>(nullptr, adj, dinv, bufB, WT2, b2, bufA, nullptr);
    gcn_layer<128, true,  false><<<512, 256, 0, stream>>>(nullptr, adj, dinv, bufA, WT3, b3, nullptr, out);
  }
}